// Round 16
// baseline (49.316 us; speedup 1.0000x reference)
//
#include <hip/hip_runtime.h>
#include <math.h>

// Problem constants (fixed by harness)
#define BB   32
#define LL   8192
#define CC   32
#define NTOK 1023      // (L-16)/8 + 1
#define KK   16
#define HID  32

typedef short  bf16x8 __attribute__((ext_vector_type(8)));
typedef float  f32x4v __attribute__((ext_vector_type(4)));
typedef unsigned int u32;
typedef unsigned short ushort_t;

__device__ __forceinline__ float4 f4add(float4 a, float4 b) {
    return make_float4(a.x + b.x, a.y + b.y, a.z + b.z, a.w + b.w);
}
__device__ __forceinline__ float4 f4fma(float4 a, float4 b, float4 c) {
    return make_float4(fmaf(a.x, b.x, c.x), fmaf(a.y, b.y, c.y),
                       fmaf(a.z, b.z, c.z), fmaf(a.w, b.w, c.w));
}
__device__ __forceinline__ float4 shflx4(float4 v, int m) {
    return make_float4(__shfl_xor(v.x, m, 64), __shfl_xor(v.y, m, 64),
                       __shfl_xor(v.z, m, 64), __shfl_xor(v.w, m, 64));
}
__device__ __forceinline__ float ex2(float x) {
    return __builtin_amdgcn_exp2f(x);             // raw v_exp_f32
}
__device__ __forceinline__ u32 pkbf16(float a, float b) {
    u32 r;
    asm("v_cvt_pk_bf16_f32 %0, %1, %2" : "=v"(r) : "v"(a), "v"(b));
    return r;                                      // low16=bf16(a), hi16=bf16(b)
}
// non-temporal float4 (single-use streams: keep them out of L2's way)
__device__ __forceinline__ float4 ntload4(const float4* p) {
    f32x4v v = __builtin_nontemporal_load((const f32x4v*)p);
    return make_float4(v.x, v.y, v.z, v.w);
}
__device__ __forceinline__ void ntstore4(float4* p, float4 v) {
    f32x4v w = {v.x, v.y, v.z, v.w};
    __builtin_nontemporal_store(w, (f32x4v*)p);
}

// ---------------- kA_fused: stats (1024 blocks) + alpha MFMA (2048 blocks) ----
// idx%3==0 -> stats block q3=idx/3 in [0,1024): (b=q3>>5, s=q3&31) register
//   partials, token stats via LDS partials, halo via wave-0 shuffle.
// else -> alpha block a_id = 2*q3+(idx%3-1) in [0,2048): (b = a_id>>6,
//   n-tile n0 = (a_id&63)*16). Wave wv owns channels 8wv..8wv+7; per iter:
//   1KB contiguous ff read (2-deep prefetch), cvt_pk->B-frag, 2x
//   mfma_16x16x32_bf16 (b1 in C), gelu, w2-dot, shfl-reduce, sigmoid ->
//   LDS tile [32c][17]; epilogue writes one coalesced 2KB [b][n][c] chunk.
// x/ff loads are NON-TEMPORAL (read-once; keeps L2 for reused data).
__global__ void __launch_bounds__(256)
kA_fused(const float* __restrict__ x,  const float* __restrict__ ff,
         const float* __restrict__ w1g, const float* __restrict__ b1,
         const float* __restrict__ w2,  const float* __restrict__ b2,
         float* __restrict__ ps, float* __restrict__ pq,
         float* __restrict__ mu_l, float* __restrict__ rstd_l,
         float* __restrict__ alpha_t) {
    __shared__ float4 smem4[592];          // 9472 B (union: stats / alpha tile)
    int t   = threadIdx.x;
    int idx = blockIdx.x;
    int r3  = idx % 3, q3 = idx / 3;

    if (r3 == 0) {
        // ================= stats =================
        float4* part_s = smem4;            // [32 rgrp][8 c4]
        float4* part_q = part_s + 256;
        float4* halo_s = part_q + 256;     // [8 c4]
        float4* halo_q = halo_s + 8;
        float4* wred_s = halo_q + 8;       // [4 wave][8 c4]
        float4* wred_q = wred_s + 32;

        int b  = q3 >> 5;
        int s  = q3 & 31;
        int c4 = t & 7, rgrp = t >> 3;
        const float4* xb = (const float4*)x + ((size_t)b * LL + s * 256) * 8;

        float4 v[8];
#pragma unroll
        for (int k = 0; k < 8; ++k)
            v[k] = ntload4(&xb[(rgrp * 8 + k) * 8 + c4]);
        float4 s4 = make_float4(0.f, 0.f, 0.f, 0.f);
        float4 q4 = make_float4(0.f, 0.f, 0.f, 0.f);
#pragma unroll
        for (int k = 0; k < 8; ++k) {
            s4 = f4add(s4, v[k]);
            q4 = f4fma(v[k], v[k], q4);
        }
        part_s[t] = s4;                    // t == rgrp*8 + c4
        part_q[t] = q4;

        // halo: 8 rows after the slice (wave 0 only; zeros for s==31)
        if (t < 64) {
            float4 hs = make_float4(0.f, 0.f, 0.f, 0.f);
            float4 hq = make_float4(0.f, 0.f, 0.f, 0.f);
            if (s < 31) {
                float4 hv = ntload4(&xb[(256 + (t >> 3)) * 8 + c4]);
                hs = hv; hq = f4fma(hv, hv, hq);
            }
            hs = f4add(hs, shflx4(hs, 8));  hq = f4add(hq, shflx4(hq, 8));
            hs = f4add(hs, shflx4(hs, 16)); hq = f4add(hq, shflx4(hq, 16));
            hs = f4add(hs, shflx4(hs, 32)); hq = f4add(hq, shflx4(hq, 32));
            if (t < 8) { halo_s[t] = hs; halo_q[t] = hq; }
        }

        // global partials: reduce over rgrp bits
        float4 gs = s4, gq = q4;
        gs = f4add(gs, shflx4(gs, 8));  gq = f4add(gq, shflx4(gq, 8));
        gs = f4add(gs, shflx4(gs, 16)); gq = f4add(gq, shflx4(gq, 16));
        gs = f4add(gs, shflx4(gs, 32)); gq = f4add(gq, shflx4(gq, 32));
        if ((t & 56) == 0) {               // one lane per (wave, c4)
            wred_s[(t >> 6) * 8 + c4] = gs;
            wred_q[(t >> 6) * 8 + c4] = gq;
        }
        __syncthreads();

        // token stats: token nl = t>>3 needs rgrps nl and nl+1 (32 = halo)
        int nl = t >> 3;
        int n  = s * 32 + nl;
        if (n < NTOK) {
            float4 a  = (nl < 31) ? part_s[(nl + 1) * 8 + c4] : halo_s[c4];
            float4 bq = (nl < 31) ? part_q[(nl + 1) * 8 + c4] : halo_q[c4];
            float4 ts = f4add(part_s[t], a);
            float4 tq = f4add(part_q[t], bq);
            float4 mu = make_float4(ts.x * 0.0625f, ts.y * 0.0625f,
                                    ts.z * 0.0625f, ts.w * 0.0625f);
            float4 var;
            var.x = fmaxf(fmaf(-mu.x, mu.x, tq.x * 0.0625f), 1e-4f);
            var.y = fmaxf(fmaf(-mu.y, mu.y, tq.y * 0.0625f), 1e-4f);
            var.z = fmaxf(fmaf(-mu.z, mu.z, tq.z * 0.0625f), 1e-4f);
            var.w = fmaxf(fmaf(-mu.w, mu.w, tq.w * 0.0625f), 1e-4f);
            float4 rs = make_float4(1.f / sqrtf(var.x), 1.f / sqrtf(var.y),
                                    1.f / sqrtf(var.z), 1.f / sqrtf(var.w));
            size_t o = (size_t)(b * NTOK + n) * 8 + c4;
            ((float4*)mu_l)[o]   = mu;
            ((float4*)rstd_l)[o] = rs;
        }

        // global partial write (indexed by q3 = b*32+s, matches k4 prologue)
        if (t < 8) {
            float4 a = f4add(f4add(wred_s[t], wred_s[8 + t]),
                             f4add(wred_s[16 + t], wred_s[24 + t]));
            float4 c = f4add(f4add(wred_q[t], wred_q[8 + t]),
                             f4add(wred_q[16 + t], wred_q[24 + t]));
            ((float4*)ps)[q3 * 8 + t] = a;
            ((float4*)pq)[q3 * 8 + t] = c;
        }
    } else {
        // ================= alpha MFMA =================
        float* als = (float*)smem4;            // [32 c][17] padded alpha tile
        int a_id = q3 * 2 + (r3 - 1);          // 0..2047
        int b    = a_id >> 6;
        int n0   = (a_id & 63) * 16;
        int l  = t & 63, wv = t >> 6;
        bool active = (l < 32);

        // A-fragment build in-wave (w1 is 2KB, L2-hot; RNE via v_cvt_pk_bf16)
        int kb = 8 * ((l >> 4) & 1);           // valid k-base for all lanes
        int j0 = l & 15;
        union { u32 w[4]; bf16x8 v; } UA0, UA1;
#pragma unroll
        for (int p = 0; p < 4; ++p) {
            float a0 = w1g[(kb + 2*p)     * HID + j0];
            float a1 = w1g[(kb + 2*p + 1) * HID + j0];
            float a2 = w1g[(kb + 2*p)     * HID + j0 + 16];
            float a3 = w1g[(kb + 2*p + 1) * HID + j0 + 16];
            u32 u0 = pkbf16(a0, a1), u1 = pkbf16(a2, a3);
            UA0.w[p] = active ? u0 : 0u;       // k>=16 lanes are the zero pad
            UA1.w[p] = active ? u1 : 0u;
        }
        bf16x8 Alo = UA0.v, Ahi = UA1.v;

        int jg = 4 * (l >> 4);
        f32x4v b1lo = *(const f32x4v*)(b1 + jg);
        f32x4v b1hi = *(const f32x4v*)(b1 + 16 + jg);
        f32x4v w2lo = *(const f32x4v*)(w2 + jg);
        f32x4v w2hi = *(const f32x4v*)(w2 + 16 + jg);
        float b2s = b2[0];

        const float C0 = -2.302211325f;    // -1.5957691216 * log2(e)
        const float C1 = -0.102943702f;    // -0.0713548162 * log2(e)

        // wave wv: channel c0 = 8*wv + it per iteration; 16 n-rows per iter
        int nlane = min(n0 + (l & 15), NTOK - 1);   // per-lane row clamp
        size_t cbase = (size_t)(b * 32 + 8 * wv) * NTOK;
        const float4* fpc = (const float4*)ff + (cbase + nlane) * 4
                          + ((l >> 4) & 1) * 2;
        const int STRD = NTOK * 4;                  // float4s per channel step

        // 2-deep prefetch over 8 iterations
        float4 a0 = ntload4(&fpc[0]),    a1 = ntload4(&fpc[1]);
        float4 p0 = ntload4(&fpc[STRD]), p1 = ntload4(&fpc[STRD + 1]);

        for (int it = 0; it < 8; ++it) {
            float4 f0 = a0, f1 = a1;
            a0 = p0; a1 = p1;
            if (it < 6) {
                p0 = ntload4(&fpc[2 * STRD]);
                p1 = ntload4(&fpc[2 * STRD + 1]);
            }
            fpc += STRD;

            union { u32 w[4]; bf16x8 v; } B;
            u32 w0 = pkbf16(f0.x, f0.y), w1v = pkbf16(f0.z, f0.w);
            u32 w2v = pkbf16(f1.x, f1.y), w3 = pkbf16(f1.z, f1.w);
            B.w[0] = active ? w0 : 0u;  B.w[1] = active ? w1v : 0u;
            B.w[2] = active ? w2v : 0u; B.w[3] = active ? w3 : 0u;

            f32x4v d0 = __builtin_amdgcn_mfma_f32_16x16x32_bf16(Alo, B.v, b1lo, 0, 0, 0);
            f32x4v d1 = __builtin_amdgcn_mfma_f32_16x16x32_bf16(Ahi, B.v, b1hi, 0, 0, 0);

            float partial = 0.f;
#pragma unroll
            for (int r = 0; r < 4; ++r) {
                float h  = d0[r];
                float a  = fmaf(h * h, C1, C0);
                float g  = h * __builtin_amdgcn_rcpf(1.0f + ex2(a * h));
                partial  = fmaf(g, w2lo[r], partial);
                float h2 = d1[r];
                float a2 = fmaf(h2 * h2, C1, C0);
                float g2 = h2 * __builtin_amdgcn_rcpf(1.0f + ex2(a2 * h2));
                partial  = fmaf(g2, w2hi[r], partial);
            }
            partial += __shfl_xor(partial, 16, 64);
            partial += __shfl_xor(partial, 32, 64);
            float outv = b2s + partial;
            float av = __builtin_amdgcn_rcpf(1.0f + ex2(-1.44269504f * outv));
            if (l < 16) als[(8 * wv + it) * 17 + l] = av;   // als[c][n-off]
        }
        __syncthreads();

        // coalesced [b][n][c] write: 512 contiguous floats, float2 per thread
        int flat = t * 2;
        int nn = flat >> 5, cc = flat & 31;
        if (n0 + nn < NTOK) {
            float2 o;
            o.x = als[cc * 17 + nn];
            o.y = als[(cc + 1) * 17 + nn];
            *(float2*)(alpha_t + ((size_t)(b * NTOK + n0 + nn)) * CC + cc) = o;
        }
    }
}

// ---------------- K4: normalize + mix + affine, inline global-stat finish ----
// 4096 blocks x 512 float4 (2 chunks/block): halves the per-block ps/pq
// prologue traffic. x load + out store are NON-TEMPORAL (single-use streams);
// mu_l/rstd_l/alpha stay cacheable (8x reuse + just written by kA).
__global__ void __launch_bounds__(256)
k4_main(const float4* __restrict__ x4,
        const float* __restrict__ ps, const float* __restrict__ pq,
        const float4* __restrict__ mul4, const float4* __restrict__ rsl4,
        const float4* __restrict__ al4,
        const float4* __restrict__ sc4, const float4* __restrict__ bi4,
        float4* __restrict__ out4) {
    __shared__ float red_s[8][32], red_q[8][32];
    __shared__ float mugs[32], rsgs[32];
    int t  = threadIdx.x;
    int b  = blockIdx.x >> 7;           // 512 float4/block; 128 blocks/batch

    {   // global-stat finish (deterministic fixed-order reduction)
        int c = t & 31, grp = t >> 5;
        float s = 0.f, q = 0.f;
#pragma unroll
        for (int i = 0; i < 4; ++i) {
            int sl = grp * 4 + i;
            s += ps[(b * 32 + sl) * 32 + c];
            q += pq[(b * 32 + sl) * 32 + c];
        }
        red_s[grp][c] = s; red_q[grp][c] = q;
        __syncthreads();
        if (t < 32) {
            float ss = 0.f, qq = 0.f;
#pragma unroll
            for (int g = 0; g < 8; ++g) { ss += red_s[g][t]; qq += red_q[g][t]; }
            float mu  = ss * (1.0f / LL);
            float var = fmaxf(qq * (1.0f / LL) - mu * mu, 1e-4f);
            mugs[t] = mu;
            rsgs[t] = 1.0f / sqrtf(var);
        }
        __syncthreads();
    }

#pragma unroll
    for (int ch = 0; ch < 2; ++ch) {
        int i4 = blockIdx.x * 512 + ch * 256 + t;
        int c4 = i4 & 7;
        int l  = (i4 >> 3) & (LL - 1);
        int n  = (l >= 5) ? min((l - 5) >> 3, NTOK - 1) : 0;

        float4 xv = ntload4(&x4[i4]);
        float4 mg = *(const float4*)(mugs + 4 * c4);
        float4 rg = *(const float4*)(rsgs + 4 * c4);
        int o4 = (b * NTOK + n) * 8 + c4;
        float4 ml = mul4[o4], rl = rsl4[o4], av = al4[o4];
        float4 s  = sc4[c4],  bi = bi4[c4];

        float4 y;
        {
            float xg = fminf(fmaxf((xv.x - mg.x) * rg.x, -30.f), 30.f);
            float xl = fminf(fmaxf((xv.x - ml.x) * rl.x, -30.f), 30.f);
            y.x = fmaf(av.x, xl - xg, xg) * s.x + bi.x;
        }
        {
            float xg = fminf(fmaxf((xv.y - mg.y) * rg.y, -30.f), 30.f);
            float xl = fminf(fmaxf((xv.y - ml.y) * rl.y, -30.f), 30.f);
            y.y = fmaf(av.y, xl - xg, xg) * s.y + bi.y;
        }
        {
            float xg = fminf(fmaxf((xv.z - mg.z) * rg.z, -30.f), 30.f);
            float xl = fminf(fmaxf((xv.z - ml.z) * rl.z, -30.f), 30.f);
            y.z = fmaf(av.z, xl - xg, xg) * s.z + bi.z;
        }
        {
            float xg = fminf(fmaxf((xv.w - mg.w) * rg.w, -30.f), 30.f);
            float xl = fminf(fmaxf((xv.w - ml.w) * rl.w, -30.f), 30.f);
            y.w = fmaf(av.w, xl - xg, xg) * s.w + bi.w;
        }
        ntstore4(&out4[i4], y);
    }
}

extern "C" void kernel_launch(void* const* d_in, const int* in_sizes, int n_in,
                              void* d_out, int out_size, void* d_ws, size_t ws_size,
                              hipStream_t stream) {
    const float* x    = (const float*)d_in[0];
    const float* ff   = (const float*)d_in[1];
    const float* aw1  = (const float*)d_in[2];
    const float* ab1  = (const float*)d_in[3];
    const float* aw2  = (const float*)d_in[4];
    const float* ab2  = (const float*)d_in[5];
    // d_in[6..9] = beta weights: dead code in the reference output
    const float* scal = (const float*)d_in[10];
    const float* bias = (const float*)d_in[11];
    float* out = (float*)d_out;

    float* wsf     = (float*)d_ws;
    float* ps      = wsf;                        //   32768 ((b,s,c))
    float* pq      = wsf + 32768;                //   32768
    float* mu_l    = wsf + 65536;                // 1047552
    float* rstd_l  = mu_l    + 1047552;          // 1047552
    float* alpha_t = rstd_l  + 1047552;          // 1047552  ([b][n][c])
    // total ~3.21M floats = 12.25 MB of d_ws

    kA_fused<<<3072, 256, 0, stream>>>(x, ff, aw1, ab1, aw2, ab2,
                                       ps, pq, mu_l, rstd_l, alpha_t);
    k4_main<<<4096, 256, 0, stream>>>((const float4*)x, ps, pq,
                                      (const float4*)mu_l, (const float4*)rstd_l,
                                      (const float4*)alpha_t,
                                      (const float4*)scal, (const float4*)bias,
                                      (float4*)out);
}

// Round 17
// 41.608 us; speedup vs baseline: 1.1853x; 1.1853x over previous
//
#include <hip/hip_runtime.h>
#include <math.h>

// Problem constants (fixed by harness)
#define BB   32
#define LL   8192
#define CC   32
#define NTOK 1023      // (L-16)/8 + 1
#define KK   16
#define HID  32

typedef short  bf16x8 __attribute__((ext_vector_type(8)));
typedef float  f32x4v __attribute__((ext_vector_type(4)));
typedef unsigned int u32;
typedef unsigned short ushort_t;

__device__ __forceinline__ float4 f4add(float4 a, float4 b) {
    return make_float4(a.x + b.x, a.y + b.y, a.z + b.z, a.w + b.w);
}
__device__ __forceinline__ float4 f4fma(float4 a, float4 b, float4 c) {
    return make_float4(fmaf(a.x, b.x, c.x), fmaf(a.y, b.y, c.y),
                       fmaf(a.z, b.z, c.z), fmaf(a.w, b.w, c.w));
}
__device__ __forceinline__ float4 shflx4(float4 v, int m) {
    return make_float4(__shfl_xor(v.x, m, 64), __shfl_xor(v.y, m, 64),
                       __shfl_xor(v.z, m, 64), __shfl_xor(v.w, m, 64));
}
__device__ __forceinline__ float ex2(float x) {
    return __builtin_amdgcn_exp2f(x);             // raw v_exp_f32
}
__device__ __forceinline__ u32 pkbf16(float a, float b) {
    u32 r;
    asm("v_cvt_pk_bf16_f32 %0, %1, %2" : "=v"(r) : "v"(a), "v"(b));
    return r;                                      // low16=bf16(a), hi16=bf16(b)
}

// NOTE (r16 post-mortem): do NOT mark x/ff/out non-temporal. x is read by
// BOTH kernels (33.5MB, L3-resident between them) and nt bypassed the
// Infinity Cache: 42.5 -> 49.3us regression. Reverted to the r15 best.

// ---------------- kA_fused: stats (1024 blocks) + alpha MFMA (2048 blocks) ----
// idx%3==0 -> stats block q3=idx/3 in [0,1024): (b=q3>>5, s=q3&31) register
//   partials, token stats via LDS partials, halo via wave-0 shuffle.
// else -> alpha block a_id = 2*q3+(idx%3-1) in [0,2048): (b = a_id>>6,
//   n-tile n0 = (a_id&63)*16). Wave wv owns channels 8wv..8wv+7; per iter:
//   1KB contiguous ff read (2-deep prefetch), cvt_pk->B-frag, 2x
//   mfma_16x16x32_bf16 (b1 in C), gelu, w2-dot, shfl-reduce, sigmoid ->
//   LDS tile [32c][17]; epilogue writes one coalesced 2KB [b][n][c] chunk.
__global__ void __launch_bounds__(256)
kA_fused(const float* __restrict__ x,  const float* __restrict__ ff,
         const float* __restrict__ w1g, const float* __restrict__ b1,
         const float* __restrict__ w2,  const float* __restrict__ b2,
         float* __restrict__ ps, float* __restrict__ pq,
         float* __restrict__ mu_l, float* __restrict__ rstd_l,
         float* __restrict__ alpha_t) {
    __shared__ float4 smem4[592];          // 9472 B (union: stats / alpha tile)
    int t   = threadIdx.x;
    int idx = blockIdx.x;
    int r3  = idx % 3, q3 = idx / 3;

    if (r3 == 0) {
        // ================= stats =================
        float4* part_s = smem4;            // [32 rgrp][8 c4]
        float4* part_q = part_s + 256;
        float4* halo_s = part_q + 256;     // [8 c4]
        float4* halo_q = halo_s + 8;
        float4* wred_s = halo_q + 8;       // [4 wave][8 c4]
        float4* wred_q = wred_s + 32;

        int b  = q3 >> 5;
        int s  = q3 & 31;
        int c4 = t & 7, rgrp = t >> 3;
        const float4* xb = (const float4*)x + ((size_t)b * LL + s * 256) * 8;

        float4 v[8];
#pragma unroll
        for (int k = 0; k < 8; ++k)
            v[k] = xb[(rgrp * 8 + k) * 8 + c4];
        float4 s4 = make_float4(0.f, 0.f, 0.f, 0.f);
        float4 q4 = make_float4(0.f, 0.f, 0.f, 0.f);
#pragma unroll
        for (int k = 0; k < 8; ++k) {
            s4 = f4add(s4, v[k]);
            q4 = f4fma(v[k], v[k], q4);
        }
        part_s[t] = s4;                    // t == rgrp*8 + c4
        part_q[t] = q4;

        // halo: 8 rows after the slice (wave 0 only; zeros for s==31)
        if (t < 64) {
            float4 hs = make_float4(0.f, 0.f, 0.f, 0.f);
            float4 hq = make_float4(0.f, 0.f, 0.f, 0.f);
            if (s < 31) {
                float4 hv = xb[(256 + (t >> 3)) * 8 + c4];
                hs = hv; hq = f4fma(hv, hv, hq);
            }
            hs = f4add(hs, shflx4(hs, 8));  hq = f4add(hq, shflx4(hq, 8));
            hs = f4add(hs, shflx4(hs, 16)); hq = f4add(hq, shflx4(hq, 16));
            hs = f4add(hs, shflx4(hs, 32)); hq = f4add(hq, shflx4(hq, 32));
            if (t < 8) { halo_s[t] = hs; halo_q[t] = hq; }
        }

        // global partials: reduce over rgrp bits
        float4 gs = s4, gq = q4;
        gs = f4add(gs, shflx4(gs, 8));  gq = f4add(gq, shflx4(gq, 8));
        gs = f4add(gs, shflx4(gs, 16)); gq = f4add(gq, shflx4(gq, 16));
        gs = f4add(gs, shflx4(gs, 32)); gq = f4add(gq, shflx4(gq, 32));
        if ((t & 56) == 0) {               // one lane per (wave, c4)
            wred_s[(t >> 6) * 8 + c4] = gs;
            wred_q[(t >> 6) * 8 + c4] = gq;
        }
        __syncthreads();

        // token stats: token nl = t>>3 needs rgrps nl and nl+1 (32 = halo)
        int nl = t >> 3;
        int n  = s * 32 + nl;
        if (n < NTOK) {
            float4 a  = (nl < 31) ? part_s[(nl + 1) * 8 + c4] : halo_s[c4];
            float4 bq = (nl < 31) ? part_q[(nl + 1) * 8 + c4] : halo_q[c4];
            float4 ts = f4add(part_s[t], a);
            float4 tq = f4add(part_q[t], bq);
            float4 mu = make_float4(ts.x * 0.0625f, ts.y * 0.0625f,
                                    ts.z * 0.0625f, ts.w * 0.0625f);
            float4 var;
            var.x = fmaxf(fmaf(-mu.x, mu.x, tq.x * 0.0625f), 1e-4f);
            var.y = fmaxf(fmaf(-mu.y, mu.y, tq.y * 0.0625f), 1e-4f);
            var.z = fmaxf(fmaf(-mu.z, mu.z, tq.z * 0.0625f), 1e-4f);
            var.w = fmaxf(fmaf(-mu.w, mu.w, tq.w * 0.0625f), 1e-4f);
            float4 rs = make_float4(1.f / sqrtf(var.x), 1.f / sqrtf(var.y),
                                    1.f / sqrtf(var.z), 1.f / sqrtf(var.w));
            size_t o = (size_t)(b * NTOK + n) * 8 + c4;
            ((float4*)mu_l)[o]   = mu;
            ((float4*)rstd_l)[o] = rs;
        }

        // global partial write (indexed by q3 = b*32+s, matches k4 prologue)
        if (t < 8) {
            float4 a = f4add(f4add(wred_s[t], wred_s[8 + t]),
                             f4add(wred_s[16 + t], wred_s[24 + t]));
            float4 c = f4add(f4add(wred_q[t], wred_q[8 + t]),
                             f4add(wred_q[16 + t], wred_q[24 + t]));
            ((float4*)ps)[q3 * 8 + t] = a;
            ((float4*)pq)[q3 * 8 + t] = c;
        }
    } else {
        // ================= alpha MFMA =================
        float* als = (float*)smem4;            // [32 c][17] padded alpha tile
        int a_id = q3 * 2 + (r3 - 1);          // 0..2047
        int b    = a_id >> 6;
        int n0   = (a_id & 63) * 16;
        int l  = t & 63, wv = t >> 6;
        bool active = (l < 32);

        // A-fragment build in-wave (w1 is 2KB, L2-hot; RNE via v_cvt_pk_bf16)
        int kb = 8 * ((l >> 4) & 1);           // valid k-base for all lanes
        int j0 = l & 15;
        union { u32 w[4]; bf16x8 v; } UA0, UA1;
#pragma unroll
        for (int p = 0; p < 4; ++p) {
            float a0 = w1g[(kb + 2*p)     * HID + j0];
            float a1 = w1g[(kb + 2*p + 1) * HID + j0];
            float a2 = w1g[(kb + 2*p)     * HID + j0 + 16];
            float a3 = w1g[(kb + 2*p + 1) * HID + j0 + 16];
            u32 u0 = pkbf16(a0, a1), u1 = pkbf16(a2, a3);
            UA0.w[p] = active ? u0 : 0u;       // k>=16 lanes are the zero pad
            UA1.w[p] = active ? u1 : 0u;
        }
        bf16x8 Alo = UA0.v, Ahi = UA1.v;

        int jg = 4 * (l >> 4);
        f32x4v b1lo = *(const f32x4v*)(b1 + jg);
        f32x4v b1hi = *(const f32x4v*)(b1 + 16 + jg);
        f32x4v w2lo = *(const f32x4v*)(w2 + jg);
        f32x4v w2hi = *(const f32x4v*)(w2 + 16 + jg);
        float b2s = b2[0];

        const float C0 = -2.302211325f;    // -1.5957691216 * log2(e)
        const float C1 = -0.102943702f;    // -0.0713548162 * log2(e)

        // wave wv: channel c0 = 8*wv + it per iteration; 16 n-rows per iter
        int nlane = min(n0 + (l & 15), NTOK - 1);   // per-lane row clamp
        size_t cbase = (size_t)(b * 32 + 8 * wv) * NTOK;
        const float4* fpc = (const float4*)ff + (cbase + nlane) * 4
                          + ((l >> 4) & 1) * 2;
        const int STRD = NTOK * 4;                  // float4s per channel step

        // 2-deep prefetch over 8 iterations
        float4 a0 = fpc[0],     a1 = fpc[1];
        float4 p0 = fpc[STRD],  p1 = fpc[STRD + 1];

        for (int it = 0; it < 8; ++it) {
            float4 f0 = a0, f1 = a1;
            a0 = p0; a1 = p1;
            if (it < 6) { p0 = fpc[2 * STRD]; p1 = fpc[2 * STRD + 1]; }
            fpc += STRD;

            union { u32 w[4]; bf16x8 v; } B;
            u32 w0 = pkbf16(f0.x, f0.y), w1v = pkbf16(f0.z, f0.w);
            u32 w2v = pkbf16(f1.x, f1.y), w3 = pkbf16(f1.z, f1.w);
            B.w[0] = active ? w0 : 0u;  B.w[1] = active ? w1v : 0u;
            B.w[2] = active ? w2v : 0u; B.w[3] = active ? w3 : 0u;

            f32x4v d0 = __builtin_amdgcn_mfma_f32_16x16x32_bf16(Alo, B.v, b1lo, 0, 0, 0);
            f32x4v d1 = __builtin_amdgcn_mfma_f32_16x16x32_bf16(Ahi, B.v, b1hi, 0, 0, 0);

            float partial = 0.f;
#pragma unroll
            for (int r = 0; r < 4; ++r) {
                float h  = d0[r];
                float a  = fmaf(h * h, C1, C0);
                float g  = h * __builtin_amdgcn_rcpf(1.0f + ex2(a * h));
                partial  = fmaf(g, w2lo[r], partial);
                float h2 = d1[r];
                float a2 = fmaf(h2 * h2, C1, C0);
                float g2 = h2 * __builtin_amdgcn_rcpf(1.0f + ex2(a2 * h2));
                partial  = fmaf(g2, w2hi[r], partial);
            }
            partial += __shfl_xor(partial, 16, 64);
            partial += __shfl_xor(partial, 32, 64);
            float outv = b2s + partial;
            float av = __builtin_amdgcn_rcpf(1.0f + ex2(-1.44269504f * outv));
            if (l < 16) als[(8 * wv + it) * 17 + l] = av;   // als[c][n-off]
        }
        __syncthreads();

        // coalesced [b][n][c] write: 512 contiguous floats, float2 per thread
        int flat = t * 2;
        int nn = flat >> 5, cc = flat & 31;
        if (n0 + nn < NTOK) {
            float2 o;
            o.x = als[cc * 17 + nn];
            o.y = als[(cc + 1) * 17 + nn];
            *(float2*)(alpha_t + ((size_t)(b * NTOK + n0 + nn)) * CC + cc) = o;
        }
    }
}

// ---------------- K4: normalize + mix + affine, inline global-stat finish ----
__global__ void __launch_bounds__(256)
k4_main(const float4* __restrict__ x4,
        const float* __restrict__ ps, const float* __restrict__ pq,
        const float4* __restrict__ mul4, const float4* __restrict__ rsl4,
        const float4* __restrict__ al4,
        const float4* __restrict__ sc4, const float4* __restrict__ bi4,
        float4* __restrict__ out4) {
    __shared__ float red_s[8][32], red_q[8][32];
    __shared__ float mugs[32], rsgs[32];
    int t  = threadIdx.x;
    int i4 = blockIdx.x * 256 + t;
    int b  = i4 >> 16;                  // L*C/4 = 65536 per batch; const per block

    {   // global-stat finish (deterministic fixed-order reduction)
        int c = t & 31, grp = t >> 5;
        float s = 0.f, q = 0.f;
#pragma unroll
        for (int i = 0; i < 4; ++i) {
            int sl = grp * 4 + i;
            s += ps[(b * 32 + sl) * 32 + c];
            q += pq[(b * 32 + sl) * 32 + c];
        }
        red_s[grp][c] = s; red_q[grp][c] = q;
        __syncthreads();
        if (t < 32) {
            float ss = 0.f, qq = 0.f;
#pragma unroll
            for (int g = 0; g < 8; ++g) { ss += red_s[g][t]; qq += red_q[g][t]; }
            float mu  = ss * (1.0f / LL);
            float var = fmaxf(qq * (1.0f / LL) - mu * mu, 1e-4f);
            mugs[t] = mu;
            rsgs[t] = 1.0f / sqrtf(var);
        }
        __syncthreads();
    }

    int c4 = i4 & 7;
    int l  = (i4 >> 3) & (LL - 1);
    int n  = (l >= 5) ? min((l - 5) >> 3, NTOK - 1) : 0;

    float4 xv = x4[i4];
    float4 mg = *(const float4*)(mugs + 4 * c4);
    float4 rg = *(const float4*)(rsgs + 4 * c4);
    int o4 = (b * NTOK + n) * 8 + c4;
    float4 ml = mul4[o4], rl = rsl4[o4], av = al4[o4];
    float4 s  = sc4[c4],  bi = bi4[c4];

    float4 y;
    {
        float xg = fminf(fmaxf((xv.x - mg.x) * rg.x, -30.f), 30.f);
        float xl = fminf(fmaxf((xv.x - ml.x) * rl.x, -30.f), 30.f);
        y.x = fmaf(av.x, xl - xg, xg) * s.x + bi.x;
    }
    {
        float xg = fminf(fmaxf((xv.y - mg.y) * rg.y, -30.f), 30.f);
        float xl = fminf(fmaxf((xv.y - ml.y) * rl.y, -30.f), 30.f);
        y.y = fmaf(av.y, xl - xg, xg) * s.y + bi.y;
    }
    {
        float xg = fminf(fmaxf((xv.z - mg.z) * rg.z, -30.f), 30.f);
        float xl = fminf(fmaxf((xv.z - ml.z) * rl.z, -30.f), 30.f);
        y.z = fmaf(av.z, xl - xg, xg) * s.z + bi.z;
    }
    {
        float xg = fminf(fmaxf((xv.w - mg.w) * rg.w, -30.f), 30.f);
        float xl = fminf(fmaxf((xv.w - ml.w) * rl.w, -30.f), 30.f);
        y.w = fmaf(av.w, xl - xg, xg) * s.w + bi.w;
    }
    out4[i4] = y;
}

extern "C" void kernel_launch(void* const* d_in, const int* in_sizes, int n_in,
                              void* d_out, int out_size, void* d_ws, size_t ws_size,
                              hipStream_t stream) {
    const float* x    = (const float*)d_in[0];
    const float* ff   = (const float*)d_in[1];
    const float* aw1  = (const float*)d_in[2];
    const float* ab1  = (const float*)d_in[3];
    const float* aw2  = (const float*)d_in[4];
    const float* ab2  = (const float*)d_in[5];
    // d_in[6..9] = beta weights: dead code in the reference output
    const float* scal = (const float*)d_in[10];
    const float* bias = (const float*)d_in[11];
    float* out = (float*)d_out;

    float* wsf     = (float*)d_ws;
    float* ps      = wsf;                        //   32768 ((b,s,c))
    float* pq      = wsf + 32768;                //   32768
    float* mu_l    = wsf + 65536;                // 1047552
    float* rstd_l  = mu_l    + 1047552;          // 1047552
    float* alpha_t = rstd_l  + 1047552;          // 1047552  ([b][n][c])
    // total ~3.21M floats = 12.25 MB of d_ws

    kA_fused<<<3072, 256, 0, stream>>>(x, ff, aw1, ab1, aw2, ab2,
                                       ps, pq, mu_l, rstd_l, alpha_t);
    k4_main<<<8192, 256, 0, stream>>>((const float4*)x, ps, pq,
                                      (const float4*)mu_l, (const float4*)rstd_l,
                                      (const float4*)alpha_t,
                                      (const float4*)scal, (const float4*)bias,
                                      (float4*)out);
}